// Round 8
// baseline (403.446 us; speedup 1.0000x reference)
//
#include <hip/hip_runtime.h>

#define HID 128
#define NTY 8
#define SCAP 1024

typedef __attribute__((ext_vector_type(8))) short bf16x8;
typedef __attribute__((ext_vector_type(4))) float f32x4;

__device__ __forceinline__ unsigned short f2bf(float x) {
    unsigned u = __float_as_uint(x);
    u += 0x7FFF + ((u >> 16) & 1);          // RNE
    return (unsigned short)(u >> 16);
}
__device__ __forceinline__ float bf2f(unsigned short s) {
    return __uint_as_float(((unsigned)s) << 16);
}
__device__ __forceinline__ float sigmoidf_fast(float x) {
    return 1.f / (1.f + __expf(-x));
}
__device__ __forceinline__ float tanhf_fast(float x) {
    return 1.f - 2.f / (1.f + __expf(2.f * x));
}
__device__ __forceinline__ unsigned cvt_pk_bf16(float lo, float hi) {
    unsigned r;
    asm("v_cvt_pk_bf16_f32 %0, %1, %2" : "=v"(r) : "v"(lo), "v"(hi));
    return r;
}

// ---------------- fused prep: h->bf16, W->wfr frags, GRU->wpkf frags, deg8=0 ----------------
// wfr[(((t*4+kc)*8+cb)*64 + lane)*8 + e] = bf16(W[t][k][d]), d=cb*16+(lane&15), k=kc*32+(lane>>4)*8+e
// wpkf[((kc*24+g3*8+ct)*64 + lane)*8 + e]: kc<4 -> wih, kc>=4 -> whh; d=ct*16+(lane&15), kk=(lane>>4)*8+e
__global__ void conv_all_kernel(const float* __restrict__ h, unsigned short* __restrict__ hbf, int nh,
                                const float* __restrict__ W, unsigned short* __restrict__ wfr,
                                const float* __restrict__ wih, const float* __restrict__ whh,
                                unsigned short* __restrict__ wpkf,
                                int* __restrict__ deg8, int M8)
{
    int i = blockIdx.x * 256 + threadIdx.x;
    if (i < nh) { hbf[i] = f2bf(h[i]); return; }
    i -= nh;
    if (i < 131072) {
        int e = i & 7, lane = (i >> 3) & 63, cb = (i >> 9) & 7, kc = (i >> 12) & 3, t = i >> 14;
        int lr = lane & 15, quad = lane >> 4;
        int d = cb * 16 + lr;
        int k = kc * 32 + quad * 8 + e;
        wfr[i] = f2bf(W[(t << 14) + (k << 7) + d]);
        return;
    }
    i -= 131072;
    if (i < 98304) {
        int e = i & 7, lane = (i >> 3) & 63, f = i >> 9;   // f = kc*24+g3*8+ct
        int ct = f & 7, fg = f >> 3;                       // fg = kc*3+g3
        int g3 = fg % 3, kc = fg / 3;
        int lr = lane & 15, quad = lane >> 4;
        int d = ct * 16 + lr;
        int kk = quad * 8 + e;
        float v;
        if (kc < 4) v = wih[(g3 * 128 + d) * 128 + kc * 32 + kk];
        else        v = whh[(g3 * 128 + d) * 128 + (kc - 4) * 32 + kk];
        wpkf[i] = f2bf(v);
        return;
    }
    i -= 98304;
    if (i < M8) deg8[i] = 0;
}

// ---------------- counting sort by key = dst*8 + type (R2-proven kernels) ----------------
__global__ void hist8_kernel(const int* __restrict__ etype, const int* __restrict__ ei,
                             int E, int* __restrict__ deg8) {
    int stride = gridDim.x * blockDim.x;
    for (int i = blockIdx.x * blockDim.x + threadIdx.x; i < E; i += stride)
        atomicAdd(&deg8[ei[E + i] * 8 + etype[i]], 1);
}

// in-place block-local exclusive scan over seg8 + per-block sums
__global__ void scanA_kernel(int* __restrict__ seg8, int* __restrict__ bsum, int M8) {
    __shared__ int s[256];
    int i = blockIdx.x * 256 + threadIdx.x;
    int v = (i < M8) ? seg8[i] : 0;
    s[threadIdx.x] = v;
    __syncthreads();
    for (int off = 1; off < 256; off <<= 1) {
        int t = (threadIdx.x >= off) ? s[threadIdx.x - off] : 0;
        __syncthreads();
        s[threadIdx.x] += t;
        __syncthreads();
    }
    if (i < M8) seg8[i] = s[threadIdx.x] - v;
    if (threadIdx.x == 255) bsum[blockIdx.x] = s[255];
}

// generic single-block scan for up to 256*C block sums (R2-proven)
__global__ void scanBbig_kernel(int* __restrict__ bsum, int nb) {
    __shared__ int s[256];
    int tx = threadIdx.x;
    int C = (nb + 255) / 256;
    int lo = tx * C, hi = lo + C; if (hi > nb) hi = nb;
    int sum = 0;
    for (int j = lo; j < hi; ++j) sum += bsum[j];
    s[tx] = sum;
    __syncthreads();
    for (int off = 1; off < 256; off <<= 1) {
        int t = (tx >= off) ? s[tx - off] : 0;
        __syncthreads();
        s[tx] += t;
        __syncthreads();
    }
    int run = s[tx] - sum;
    for (int j = lo; j < hi; ++j) { int v = bsum[j]; bsum[j] = run; run += v; }
}

__global__ void scanC_kernel(int* __restrict__ seg8, const int* __restrict__ bsum, int M8) {
    int i = blockIdx.x * 256 + threadIdx.x;
    if (i < M8) seg8[i] += bsum[blockIdx.x];
}

// scatter: consumes seg8 cursor (atomicAdd mutates starts -> segment ENDS, reused as bounds)
__global__ void scatter8_kernel(const int* __restrict__ etype, const int* __restrict__ ei,
                                int E, int* __restrict__ seg8, int* __restrict__ sortedE) {
    int stride = gridDim.x * blockDim.x;
    for (int i = blockIdx.x * blockDim.x + threadIdx.x; i < E; i += stride) {
        int pos = atomicAdd(&seg8[ei[E + i] * 8 + etype[i]], 1);
        sortedE[pos] = ei[i];   // src node id
    }
}

// ---------------- fused: per-type aggregate (flat walk) + MFMA transform + GRU ----------------
// messages[v] = sum_t W_t * (sum_{e in (v,t)} h[src_e]) + cnt(v,t)*b_t   (linearity; R2-verified math)
// Block: 64 nodes, 512 threads. Walk = R7's 8-thread/node serial structure over the node's
// CONTIGUOUS (dst,type)-sorted row range (prefetch live across type boundaries & barriers).
// Per type: S_t slices -> As (R7 swizzle) -> barrier -> macc += W_t*S_t (16 MFMA/wave) -> barrier.
// Then bias, macc->As msg handoff (R1-verified formulas), GRU = R7 verbatim.
__global__ __launch_bounds__(512, 4) void fused_ggnn(
    const unsigned short* __restrict__ hbf, const float* __restrict__ hf,
    const int* __restrict__ sortedE, const int* __restrict__ seg8,
    const unsigned short* __restrict__ wfr, const float* __restrict__ bias,
    const unsigned short* __restrict__ wpkf, const float* __restrict__ bih,
    const float* __restrict__ bhh, float* __restrict__ out, int N)
{
    __shared__ unsigned short As[4][2048];   // per-16-node group, 128 bf16 cols, XOR-swizzled
    __shared__ int srcs_l[SCAP];
    __shared__ int bnds_l[513];

    int tx = threadIdx.x;
    int n0 = blockIdx.x * 64;
    int M8cap = N * 8;

    // bounds: start[k] = seg8[k-1] (post-scatter ends of previous), start[0] = 0
    for (int j = tx; j < 513; j += 512) {
        int k = n0 * 8 + j;
        if (k > M8cap) k = M8cap;
        bnds_l[j] = (k == 0) ? 0 : seg8[k - 1];
    }
    __syncthreads();
    int rowlo = bnds_l[0], rowhi = bnds_l[512];
    int cntb = rowhi - rowlo;
    for (int i = tx; i < cntb && i < SCAP; i += 512) srcs_l[i] = sortedE[rowlo + i];

    int lane = tx & 63, w = tx >> 6;
    int lr = lane & 15, quad = lane >> 4;
    int rt = w & 3, cg = w >> 2;            // GRU/GEMM role: 16 nodes (rt) x 64 d (cg)

    // GRU h fragments: independent loads in flight under the walk
    int gnode = n0 + rt * 16 + lr;
    bool gvalid = gnode < N;
    int gnc = gvalid ? gnode : (N - 1);
    bf16x8 afh[4];
    {
        const unsigned short* hrow = hbf + ((size_t)gnc << 7) + (quad << 3);
        #pragma unroll
        for (int k4 = 0; k4 < 4; ++k4) afh[k4] = *(const bf16x8*)&hrow[k4 * 32];
    }
    __syncthreads();   // srcs_l ready

    // walk role: 8 threads/node, 32B slice each (R7-proven structure)
    int ln = tx >> 3, j8 = tx & 7;
    int r = bnds_l[ln * 8];
    int hi_n = bnds_l[ln * 8 + 8];
    uint4 c0v, c1v;
    if (r < hi_n) {
        int ii = r - rowlo;
        int src = (ii < SCAP) ? srcs_l[ii] : sortedE[r];
        const unsigned short* p = hbf + ((size_t)src << 7) + j8 * 16;
        c0v = *(const uint4*)p;
        c1v = *(const uint4*)(p + 8);
    }

    f32x4 macc[4] = {};   // msg[node=lr][d = cg*64 + ct*16 + quad*4 + j]
    int lrw = ln & 15, wv = ln >> 4;
    int swzw = (lrw & 7) << 4;

    for (int t = 0; t < 8; ++t) {
        int re = bnds_l[ln * 8 + t + 1];
        float a[16];
        #pragma unroll
        for (int j = 0; j < 16; ++j) a[j] = 0.f;

        while (r < re) {
            uint4 p0 = c0v, p1 = c1v;
            int rn = r + 1;
            if (rn < hi_n) {
                int ii = rn - rowlo;
                int src = (ii < SCAP) ? srcs_l[ii] : sortedE[rn];
                const unsigned short* p = hbf + ((size_t)src << 7) + j8 * 16;
                c0v = *(const uint4*)p;
                c1v = *(const uint4*)(p + 8);
            }
            const unsigned short* q0 = (const unsigned short*)&p0;
            const unsigned short* q1 = (const unsigned short*)&p1;
            #pragma unroll
            for (int u = 0; u < 8; ++u) {
                a[u]     += bf2f(q0[u]);
                a[8 + u] += bf2f(q1[u]);
            }
            r = rn;
        }

        // write S_t slice to As (R7 swizzle)
        {
            unsigned short tmp[16];
            #pragma unroll
            for (int j = 0; j < 16; ++j) tmp[j] = f2bf(a[j]);
            int b0 = ((lrw << 8) + (j8 << 5)) ^ swzw;
            int b1 = ((lrw << 8) + (j8 << 5) + 16) ^ swzw;
            *(uint4*)((char*)&As[wv][0] + b0) = *(const uint4*)&tmp[0];
            *(uint4*)((char*)&As[wv][0] + b1) = *(const uint4*)&tmp[8];
        }
        __syncthreads();

        // macc += W_t * S_t  (16 MFMAs/wave; wf lane-coalesced from L2)
        {
            const unsigned short* AsW = &As[rt][0];
            const unsigned short* wt = wfr + (t << 14) + (lane << 3);
            #pragma unroll
            for (int kc = 0; kc < 4; ++kc) {
                int byte = ((lr << 8) + (kc << 6) + (quad << 4)) ^ ((lr & 7) << 4);
                bf16x8 af = *(const bf16x8*)((char*)AsW + byte);
                #pragma unroll
                for (int ct = 0; ct < 4; ++ct) {
                    int cb8 = cg * 4 + ct;
                    bf16x8 wf = *(const bf16x8*)&wt[(kc << 12) + (cb8 << 9)];
                    macc[ct] = __builtin_amdgcn_mfma_f32_16x16x32_bf16(wf, af, macc[ct], 0, 0, 0);
                }
            }
        }
        __syncthreads();
    }

    // bias: messages += cnt(node,t) * b_t   (per-lane node = rt*16+lr)
    {
        int nl = rt * 16 + lr;
        #pragma unroll
        for (int t = 0; t < 8; ++t) {
            float cnt = (float)(bnds_l[nl * 8 + t + 1] - bnds_l[nl * 8 + t]);
            #pragma unroll
            for (int ct = 0; ct < 4; ++ct) {
                int d0 = cg * 64 + ct * 16 + quad * 4;
                float4 bv = *(const float4*)&bias[t * 128 + d0];
                macc[ct][0] += cnt * bv.x;
                macc[ct][1] += cnt * bv.y;
                macc[ct][2] += cnt * bv.z;
                macc[ct][3] += cnt * bv.w;
            }
        }
    }

    // macc -> As msg handoff (R1-verified write formula; last barrier above protects As)
    {
        int swz = (lr & 7) << 4;
        #pragma unroll
        for (int ct = 0; ct < 4; ++ct) {
            int cb8 = cg * 4 + ct;
            uint2 v;
            v.x = cvt_pk_bf16(macc[ct][0], macc[ct][1]);
            v.y = cvt_pk_bf16(macc[ct][2], macc[ct][3]);
            int byte = ((lr << 8) + (cb8 << 5) + (quad << 3)) ^ swz;
            *(uint2*)((char*)&As[rt][0] + byte) = v;
        }
    }
    __syncthreads();

    // ---- GRU: single-pass parallel gates (R7 verbatim) ----
    const unsigned short* AsW = &As[rt][0];
    const unsigned short* wg = wpkf + (lane << 3);

    f32x4 aR[4] = {}, aZ[4] = {}, aI[4] = {}, aH[4] = {};
    #pragma unroll
    for (int kc = 0; kc < 8; ++kc) {
        bf16x8 af;
        if (kc < 4) {
            int byte = ((lr << 8) + (kc << 6) + (quad << 4)) ^ ((lr & 7) << 4);
            af = *(const bf16x8*)((char*)AsW + byte);
        } else {
            af = afh[kc - 4];
        }
        #pragma unroll
        for (int g3 = 0; g3 < 3; ++g3) {
            #pragma unroll
            for (int ct = 0; ct < 4; ++ct) {
                bf16x8 wf = *(const bf16x8*)&wg[(unsigned)((kc * 3 + g3) * 8 + cg * 4 + ct) << 9];
                if (g3 == 0)      aR[ct] = __builtin_amdgcn_mfma_f32_16x16x32_bf16(wf, af, aR[ct], 0, 0, 0);
                else if (g3 == 1) aZ[ct] = __builtin_amdgcn_mfma_f32_16x16x32_bf16(wf, af, aZ[ct], 0, 0, 0);
                else if (kc < 4)  aI[ct] = __builtin_amdgcn_mfma_f32_16x16x32_bf16(wf, af, aI[ct], 0, 0, 0);
                else              aH[ct] = __builtin_amdgcn_mfma_f32_16x16x32_bf16(wf, af, aH[ct], 0, 0, 0);
            }
        }
    }

    // epilogue: node = lr, d = cg*64 + ct*16 + quad*4 + reg
    if (gvalid) {
        #pragma unroll
        for (int ct = 0; ct < 4; ++ct) {
            int d0 = cg * 64 + ct * 16 + quad * 4;
            f32x4 bir = *(const f32x4*)&bih[d0],       bhr = *(const f32x4*)&bhh[d0];
            f32x4 biz = *(const f32x4*)&bih[128 + d0], bhz = *(const f32x4*)&bhh[128 + d0];
            f32x4 bin = *(const f32x4*)&bih[256 + d0], bhn = *(const f32x4*)&bhh[256 + d0];
            f32x4 h0 = *(const f32x4*)&hf[(size_t)gnode * 128 + d0];
            f32x4 o;
            #pragma unroll
            for (int j = 0; j < 4; ++j) {
                float rr = sigmoidf_fast(aR[ct][j] + bir[j] + bhr[j]);
                float zz = sigmoidf_fast(aZ[ct][j] + biz[j] + bhz[j]);
                float nn = tanhf_fast(aI[ct][j] + bin[j] + rr * (aH[ct][j] + bhn[j]));
                o[j] = (1.f - zz) * nn + zz * h0[j];
            }
            *(f32x4*)&out[(size_t)gnode * 128 + d0] = o;
        }
    }
}

extern "C" void kernel_launch(void* const* d_in, const int* in_sizes, int n_in,
                              void* d_out, int out_size, void* d_ws, size_t ws_size,
                              hipStream_t stream)
{
    const float* h     = (const float*)d_in[0];
    const int*   ei    = (const int*)d_in[1];
    const int*   etype = (const int*)d_in[2];
    const float* W     = (const float*)d_in[3];
    const float* b     = (const float*)d_in[4];
    const float* wih   = (const float*)d_in[5];
    const float* whh   = (const float*)d_in[6];
    const float* bih   = (const float*)d_in[7];
    const float* bhh   = (const float*)d_in[8];
    float* out = (float*)d_out;

    int E = in_sizes[1] / 2;
    int N = in_sizes[0] / HID;
    int M8 = N * 8;
    int nbA = (M8 + 255) / 256;

    char* p = (char*)d_ws;
    auto alloc = [&](size_t bytes) { char* r = p; p += (bytes + 255) & ~(size_t)255; return r; };
    unsigned short* hbf  = (unsigned short*)alloc((size_t)N * 128 * 2);
    unsigned short* wfr  = (unsigned short*)alloc((size_t)131072 * 2);
    unsigned short* wpkf = (unsigned short*)alloc((size_t)98304 * 2);
    int* seg8    = (int*)alloc((size_t)M8 * 4);
    int* bsum    = (int*)alloc((size_t)nbA * 4);
    int* sortedE = (int*)alloc((size_t)E * 4);
    (void)ws_size;

    int totalConv = N * 128 + 131072 + 98304 + M8;
    conv_all_kernel<<<(totalConv + 255) / 256, 256, 0, stream>>>(
        h, hbf, N * 128, W, wfr, wih, whh, wpkf, seg8, M8);

    hist8_kernel<<<1024, 256, 0, stream>>>(etype, ei, E, seg8);
    scanA_kernel<<<nbA, 256, 0, stream>>>(seg8, bsum, M8);
    scanBbig_kernel<<<1, 256, 0, stream>>>(bsum, nbA);
    scanC_kernel<<<nbA, 256, 0, stream>>>(seg8, bsum, M8);
    scatter8_kernel<<<1024, 256, 0, stream>>>(etype, ei, E, seg8, sortedE);

    fused_ggnn<<<(N + 63) / 64, 512, 0, stream>>>(hbf, h, sortedE, seg8, wfr, b,
                                                  wpkf, bih, bhh, out, N);
}

// Round 9
// 380.804 us; speedup vs baseline: 1.0595x; 1.0595x over previous
//
#include <hip/hip_runtime.h>

#define HID 128
#define NTY 8

typedef __attribute__((ext_vector_type(8))) short bf16x8;
typedef __attribute__((ext_vector_type(4))) float f32x4;

__device__ __forceinline__ unsigned short f2bf(float x) {
    unsigned u = __float_as_uint(x);
    u += 0x7FFF + ((u >> 16) & 1);          // RNE
    return (unsigned short)(u >> 16);
}
__device__ __forceinline__ float bf2f(unsigned short s) {
    return __uint_as_float(((unsigned)s) << 16);
}
__device__ __forceinline__ float sigmoidf_fast(float x) {
    return 1.f / (1.f + __expf(-x));
}
__device__ __forceinline__ float tanhf_fast(float x) {
    return 1.f - 2.f / (1.f + __expf(2.f * x));
}

// ---------------- fused prep: h->bf16, W->wfr frags, GRU->wpkf frags, sortedE=-1, seg8=0 ----------------
// wfr[(((t*4+kc)*8+cb)*64 + lane)*8 + e] = bf16(W[t][k][d]), d=cb*16+(lane&15), k=kc*32+(lane>>4)*8+e
// wpkf[((kc*24+g3*8+ct)*64 + lane)*8 + e]: kc<4 -> wih, kc>=4 -> whh; d=ct*16+(lane&15), kk=(lane>>4)*8+e
__global__ void conv_all_kernel(const float* __restrict__ h, unsigned short* __restrict__ hbf, int nh,
                                const float* __restrict__ W, unsigned short* __restrict__ wfr,
                                const float* __restrict__ wih, const float* __restrict__ whh,
                                unsigned short* __restrict__ wpkf,
                                int* __restrict__ sortedE, int capE,
                                int* __restrict__ seg8, int M8)
{
    int i = blockIdx.x * 256 + threadIdx.x;
    if (i < nh) { hbf[i] = f2bf(h[i]); return; }
    i -= nh;
    if (i < 131072) {
        int e = i & 7, lane = (i >> 3) & 63, cb = (i >> 9) & 7, kc = (i >> 12) & 3, t = i >> 14;
        int lr = lane & 15, quad = lane >> 4;
        int d = cb * 16 + lr;
        int k = kc * 32 + quad * 8 + e;
        wfr[i] = f2bf(W[(t << 14) + (k << 7) + d]);
        return;
    }
    i -= 131072;
    if (i < 98304) {
        int e = i & 7, lane = (i >> 3) & 63, f = i >> 9;   // f = kc*24+g3*8+ct
        int ct = f & 7, fg = f >> 3;                       // fg = kc*3+g3
        int g3 = fg % 3, kc = fg / 3;
        int lr = lane & 15, quad = lane >> 4;
        int d = ct * 16 + lr;
        int kk = quad * 8 + e;
        float v;
        if (kc < 4) v = wih[(g3 * 128 + d) * 128 + kc * 32 + kk];
        else        v = whh[(g3 * 128 + d) * 128 + (kc - 4) * 32 + kk];
        wpkf[i] = f2bf(v);
        return;
    }
    i -= 98304;
    if (i < capE) { sortedE[i] = -1; return; }
    i -= capE;
    if (i < M8) seg8[i] = 0;
}

// ---------------- counting sort by key = type*N + dst ----------------
__global__ void hist8_kernel(const int* __restrict__ etype, const int* __restrict__ ei,
                             int E, int N, int* __restrict__ seg8) {
    int stride = gridDim.x * blockDim.x;
    for (int i = blockIdx.x * blockDim.x + threadIdx.x; i < E; i += stride)
        atomicAdd(&seg8[etype[i] * N + ei[E + i]], 1);
}

// in-place block-local exclusive scan over seg8 + per-block sums (R8-proven)
__global__ void scanA_kernel(int* __restrict__ seg8, int* __restrict__ bsum, int M8) {
    __shared__ int s[256];
    int i = blockIdx.x * 256 + threadIdx.x;
    int v = (i < M8) ? seg8[i] : 0;
    s[threadIdx.x] = v;
    __syncthreads();
    for (int off = 1; off < 256; off <<= 1) {
        int t = (threadIdx.x >= off) ? s[threadIdx.x - off] : 0;
        __syncthreads();
        s[threadIdx.x] += t;
        __syncthreads();
    }
    if (i < M8) seg8[i] = s[threadIdx.x] - v;
    if (threadIdx.x == 255) bsum[blockIdx.x] = s[255];
}

// block-sum scan (R8-proven) + tail: per-type padded region bases (pad to 128)
__global__ void scanBbig_kernel(int* __restrict__ bsum, int nb,
                                const int* __restrict__ seg8, int N, int E,
                                int* __restrict__ padB, int* __restrict__ padA) {
    __shared__ int s[256];
    int tx = threadIdx.x;
    int C = (nb + 255) / 256;
    int lo = tx * C, hi = lo + C; if (hi > nb) hi = nb;
    int sum = 0;
    for (int j = lo; j < hi; ++j) sum += bsum[j];
    s[tx] = sum;
    __syncthreads();
    for (int off = 1; off < 256; off <<= 1) {
        int t = (tx >= off) ? s[tx - off] : 0;
        __syncthreads();
        s[tx] += t;
        __syncthreads();
    }
    int run = s[tx] - sum;
    for (int j = lo; j < hi; ++j) { int v = bsum[j]; bsum[j] = run; run += v; }
    __syncthreads();
    if (tx == 0) {
        int r[9];
        for (int t = 0; t < 8; ++t) { int k = t * N; r[t] = seg8[k] + bsum[k >> 8]; }
        r[8] = E;
        int pb = 0;
        for (int t = 0; t < 8; ++t) {
            padB[t] = pb;
            padA[t] = pb - r[t];
            int c = r[t + 1] - r[t];
            pb += (c + 127) & ~127;
        }
        padB[8] = pb;
    }
}

// finalize: seg8[k] = padded global start of segment k
__global__ void scanC_kernel(int* __restrict__ seg8, const int* __restrict__ bsum,
                             const int* __restrict__ padA, int M8, int N) {
    int i = blockIdx.x * 256 + threadIdx.x;
    if (i < M8) {
        int t = i / N;
        seg8[i] += bsum[i >> 8] + padA[t];
    }
}

// scatter: consumes seg8 cursor (atomicAdd mutates starts -> segment ENDS, reused as bounds)
__global__ void scatter8_kernel(const int* __restrict__ etype, const int* __restrict__ ei,
                                int E, int N, int* __restrict__ seg8, int* __restrict__ sortedE) {
    int stride = gridDim.x * blockDim.x;
    for (int i = blockIdx.x * blockDim.x + threadIdx.x; i < E; i += stride) {
        int pos = atomicAdd(&seg8[etype[i] * N + ei[E + i]], 1);
        sortedE[pos] = ei[i];   // src node id
    }
}

// ---------------- msg GEMM: 128-edge x 128-d tile, (type,dst)-sorted => M writes IN TILE ORDER ----------------
// Operand-swapped MFMA (R7-proven): D[d][e]; M row index = base+e (no q permutation).
__global__ __launch_bounds__(256) void msg_gemm(
    const unsigned short* __restrict__ hbf, const unsigned short* __restrict__ wfr,
    const float* __restrict__ bias, const int* __restrict__ sortedE,
    const int* __restrict__ padB, unsigned short* __restrict__ M)
{
    __shared__ unsigned short hs[128][136];
    __shared__ int srcs[128];
    __shared__ int stype;

    int tx = threadIdx.x;
    int base = blockIdx.x * 128;
    if (tx < 128) srcs[tx] = sortedE[base + tx];
    if (tx == 0) {
        int t = -1;
        #pragma unroll
        for (int tt = 0; tt < 8; ++tt)
            if (base >= padB[tt] && base < padB[tt + 1]) t = tt;
        stype = t;
    }
    __syncthreads();
    int t = stype;
    if (t < 0) return;

    for (int f = tx; f < 2048; f += 256) {
        int row = f >> 4, c8 = (f & 15) * 8;
        int s = srcs[row]; if (s < 0) s = 0;
        *(uint4*)&hs[row][c8] = *(const uint4*)&hbf[(size_t)s * 128 + c8];
    }
    __syncthreads();

    int lane = tx & 63, w = tx >> 6;
    int r0 = (w >> 1) * 64, c0 = (w & 1) * 64;   // r0: edge-tile base, c0: d-tile base
    int lr = lane & 15, quad = lane >> 4;
    f32x4 acc[4][4] = {};   // [rb(e-tile)][cb(d-tile)], D[d][e] per tile

    // W fragments lane-coalesced from L2 (R7-proven layout)
    const unsigned short* wt = wfr + (t << 14) + ((unsigned)(c0 >> 4) << 9) + (lane << 3);
    #pragma unroll
    for (int kc = 0; kc < 4; ++kc) {
        bf16x8 af[4], wf[4];
        #pragma unroll
        for (int rb = 0; rb < 4; ++rb) af[rb] = *(const bf16x8*)&hs[r0 + rb * 16 + lr][kc * 32 + quad * 8];
        #pragma unroll
        for (int cb = 0; cb < 4; ++cb) wf[cb] = *(const bf16x8*)&wt[(kc << 12) + (cb << 9)];
        #pragma unroll
        for (int rb = 0; rb < 4; ++rb)
            #pragma unroll
            for (int cb = 0; cb < 4; ++cb)
                acc[rb][cb] = __builtin_amdgcn_mfma_f32_16x16x32_bf16(wf[cb], af[rb], acc[rb][cb], 0, 0, 0);
    }

    // epilogue: e = r0+rb*16+lr, d = c0+cb*16+quad*4+reg; M row = base+e (sequential!)
    float4 bv4[4];
    #pragma unroll
    for (int cb = 0; cb < 4; ++cb)
        bv4[cb] = *(const float4*)&bias[t * 128 + c0 + cb * 16 + quad * 4];

    #pragma unroll
    for (int rb = 0; rb < 4; ++rb) {
        int e = r0 + rb * 16 + lr;
        size_t mrow = (size_t)(base + e);
        #pragma unroll
        for (int cb = 0; cb < 4; ++cb) {
            int d0 = c0 + cb * 16 + quad * 4;
            f32x4 a = acc[rb][cb];
            uint2 v;
            v.x = (unsigned)f2bf(a[0] + bv4[cb].x) | ((unsigned)f2bf(a[1] + bv4[cb].y) << 16);
            v.y = (unsigned)f2bf(a[2] + bv4[cb].z) | ((unsigned)f2bf(a[3] + bv4[cb].w) << 16);
            *(uint2*)&M[mrow * 128 + d0] = v;
        }
    }
}

// ---------------- fused seg-reduce + GRU: 64 nodes/block, 512 threads (R7 structure) ----------------
// Stage A: 8 threads/node, serial walk over the node's 8 per-type runs (contiguous within each
// type region), 1-deep prefetch carried ACROSS runs in registers — no barriers in the walk.
// GRU: single-pass parallel gates (R7 verbatim).
__global__ __launch_bounds__(512, 4) void gru_fused(
    const unsigned short* __restrict__ M, const int* __restrict__ segE,
    const int* __restrict__ padB, const unsigned short* __restrict__ hbf,
    const unsigned short* __restrict__ wpkf, const float* __restrict__ bih,
    const float* __restrict__ bhh, const float* __restrict__ hf,
    float* __restrict__ out, int N)
{
    __shared__ unsigned short As[4][2048];   // group: 16 nodes x 128 bf16 msg, XOR-swizzled
    __shared__ int bnds_l[520];              // [t][j]: start of (t, n0+j)'s run; j=64 -> end of (t, n0+63)

    int tx = threadIdx.x;
    int n0 = blockIdx.x * 64;

    // bounds: start(t,n) = segE[t*N + n-1] (ends-after-scatter), start(t,0) = padB[t]
    for (int jl = tx; jl < 520; jl += 512) {
        int t = jl / 65, j = jl - t * 65;
        int nidx = n0 + j - 1;
        int v;
        if (nidx < 0) v = padB[t];
        else {
            if (nidx > N - 1) nidx = N - 1;
            v = segE[t * N + nidx];
        }
        bnds_l[jl] = v;
    }

    int lane = tx & 63, w = tx >> 6;
    int lr = lane & 15, quad = lane >> 4;
    int rt = w & 3, cg = w >> 2;            // wave owns nodes rt*16.., d-cols cg*64..
    int node = n0 + rt * 16 + lr;
    bool valid = node < N;
    int nc = valid ? node : (N - 1);

    // prefetch h fragments early: independent global loads in flight under stage A
    bf16x8 afh[4];
    {
        const unsigned short* hrow = hbf + ((size_t)nc << 7) + (quad << 3);
        #pragma unroll
        for (int k4 = 0; k4 < 4; ++k4) afh[k4] = *(const bf16x8*)&hrow[k4 * 32];
    }
    __syncthreads();   // bnds ready

    // ---- stage A: thread (ln, j8) reduces shorts [j8*16, j8*16+16) over the node's 8 runs ----
    {
        int ln = tx >> 3, j8 = tx & 7;
        float a[16];
        #pragma unroll
        for (int j = 0; j < 16; ++j) a[j] = 0.f;

        int tcur = 0;
        int r = bnds_l[ln], re = bnds_l[ln + 1];   // t=0 row offset is 0
        while (r >= re && tcur < 7) {
            ++tcur;
            r = bnds_l[tcur * 65 + ln];
            re = bnds_l[tcur * 65 + ln + 1];
        }
        bool have = (r < re);
        uint4 c0v, c1v;
        if (have) {
            const unsigned short* p = M + (size_t)r * 128 + j8 * 16;
            c0v = *(const uint4*)p;
            c1v = *(const uint4*)(p + 8);
        }
        while (have) {
            uint4 p0 = c0v, p1 = c1v;
            // advance to next row (possibly crossing runs), prefetch it
            int rn = r + 1, tn = tcur, ren = re;
            while (rn >= ren && tn < 7) {
                ++tn;
                rn = bnds_l[tn * 65 + ln];
                ren = bnds_l[tn * 65 + ln + 1];
            }
            bool haveN = (rn < ren);
            if (haveN) {
                const unsigned short* p = M + (size_t)rn * 128 + j8 * 16;
                c0v = *(const uint4*)p;
                c1v = *(const uint4*)(p + 8);
            }
            const unsigned short* q0 = (const unsigned short*)&p0;
            const unsigned short* q1 = (const unsigned short*)&p1;
            #pragma unroll
            for (int u = 0; u < 8; ++u) {
                a[u]     += bf2f(q0[u]);
                a[8 + u] += bf2f(q1[u]);
            }
            r = rn; tcur = tn; re = ren; have = haveN;
        }

        unsigned short tmp[16];
        #pragma unroll
        for (int j = 0; j < 16; ++j) tmp[j] = f2bf(a[j]);
        int lrw = ln & 15, wv = ln >> 4;
        int swz = (lrw & 7) << 4;
        int b0 = ((lrw << 8) + (j8 << 5)) ^ swz;
        int b1 = ((lrw << 8) + (j8 << 5) + 16) ^ swz;
        *(uint4*)((char*)&As[wv][0] + b0) = *(const uint4*)&tmp[0];
        *(uint4*)((char*)&As[wv][0] + b1) = *(const uint4*)&tmp[8];
    }
    __syncthreads();

    // ---- GRU: single-pass parallel gates; 96 weight loads + 96 MFMAs per wave (R7 verbatim) ----
    const unsigned short* AsW = &As[rt][0];
    const unsigned short* wg = wpkf + (lane << 3);

    f32x4 aR[4] = {}, aZ[4] = {}, aI[4] = {}, aH[4] = {};
    #pragma unroll
    for (int kc = 0; kc < 8; ++kc) {
        bf16x8 af;
        if (kc < 4) {
            int byte = ((lr << 8) + (kc << 6) + (quad << 4)) ^ ((lr & 7) << 4);
            af = *(const bf16x8*)((char*)AsW + byte);
        } else {
            af = afh[kc - 4];
        }
        #pragma unroll
        for (int g3 = 0; g3 < 3; ++g3) {
            #pragma unroll
            for (int ct = 0; ct < 4; ++ct) {
                bf16x8 wf = *(const bf16x8*)&wg[(unsigned)((kc * 3 + g3) * 8 + cg * 4 + ct) << 9];
                if (g3 == 0)      aR[ct] = __builtin_amdgcn_mfma_f32_16x16x32_bf16(wf, af, aR[ct], 0, 0, 0);
                else if (g3 == 1) aZ[ct] = __builtin_amdgcn_mfma_f32_16x16x32_bf16(wf, af, aZ[ct], 0, 0, 0);
                else if (kc < 4)  aI[ct] = __builtin_amdgcn_mfma_f32_16x16x32_bf16(wf, af, aI[ct], 0, 0, 0);
                else              aH[ct] = __builtin_amdgcn_mfma_f32_16x16x32_bf16(wf, af, aH[ct], 0, 0, 0);
            }
        }
    }

    // ---- epilogue: node = col (lr), d = cg*64 + ct*16 + quad*4 + reg ----
    if (valid) {
        #pragma unroll
        for (int ct = 0; ct < 4; ++ct) {
            int d0 = cg * 64 + ct * 16 + quad * 4;
            f32x4 bir = *(const f32x4*)&bih[d0],       bhr = *(const f32x4*)&bhh[d0];
            f32x4 biz = *(const f32x4*)&bih[128 + d0], bhz = *(const f32x4*)&bhh[128 + d0];
            f32x4 bin = *(const f32x4*)&bih[256 + d0], bhn = *(const f32x4*)&bhh[256 + d0];
            f32x4 h0 = *(const f32x4*)&hf[(size_t)node * 128 + d0];
            f32x4 o;
            #pragma unroll
            for (int j = 0; j < 4; ++j) {
                float r  = sigmoidf_fast(aR[ct][j] + bir[j] + bhr[j]);
                float z  = sigmoidf_fast(aZ[ct][j] + biz[j] + bhz[j]);
                float nn = tanhf_fast(aI[ct][j] + bin[j] + r * (aH[ct][j] + bhn[j]));
                o[j] = (1.f - z) * nn + z * h0[j];
            }
            *(f32x4*)&out[(size_t)node * 128 + d0] = o;
        }
    }
}

extern "C" void kernel_launch(void* const* d_in, const int* in_sizes, int n_in,
                              void* d_out, int out_size, void* d_ws, size_t ws_size,
                              hipStream_t stream)
{
    const float* h     = (const float*)d_in[0];
    const int*   ei    = (const int*)d_in[1];
    const int*   etype = (const int*)d_in[2];
    const float* W     = (const float*)d_in[3];
    const float* b     = (const float*)d_in[4];
    const float* wih   = (const float*)d_in[5];
    const float* whh   = (const float*)d_in[6];
    const float* bih   = (const float*)d_in[7];
    const float* bhh   = (const float*)d_in[8];
    float* out = (float*)d_out;

    int E = in_sizes[1] / 2;
    int N = in_sizes[0] / HID;
    int M8 = N * 8;
    int nbA = (M8 + 255) / 256;
    int capE = ((E + 127) / 128 + NTY) * 128;   // upper bound on padded total

    char* p = (char*)d_ws;
    auto alloc = [&](size_t bytes) { char* r = p; p += (bytes + 255) & ~(size_t)255; return r; };
    unsigned short* hbf  = (unsigned short*)alloc((size_t)N * 128 * 2);
    unsigned short* wfr  = (unsigned short*)alloc((size_t)131072 * 2);
    unsigned short* wpkf = (unsigned short*)alloc((size_t)98304 * 2);
    int* seg8    = (int*)alloc((size_t)M8 * 4);
    int* bsum    = (int*)alloc((size_t)nbA * 4);
    int* sortedE = (int*)alloc((size_t)capE * 4);
    int* padB    = (int*)alloc(9 * 4);
    int* padA    = (int*)alloc(8 * 4);
    unsigned short* M = (unsigned short*)alloc((size_t)capE * 128 * 2);
    (void)ws_size;

    int totalConv = N * 128 + 131072 + 98304 + capE + M8;
    conv_all_kernel<<<(totalConv + 255) / 256, 256, 0, stream>>>(
        h, hbf, N * 128, W, wfr, wih, whh, wpkf, sortedE, capE, seg8, M8);

    hist8_kernel<<<1024, 256, 0, stream>>>(etype, ei, E, N, seg8);
    scanA_kernel<<<nbA, 256, 0, stream>>>(seg8, bsum, M8);
    scanBbig_kernel<<<1, 256, 0, stream>>>(bsum, nbA, seg8, N, E, padB, padA);
    scanC_kernel<<<nbA, 256, 0, stream>>>(seg8, bsum, padA, M8, N);
    scatter8_kernel<<<1024, 256, 0, stream>>>(etype, ei, E, N, seg8, sortedE);

    msg_gemm<<<capE / 128, 256, 0, stream>>>(hbf, wfr, b, sortedE, padB, M);
    gru_fused<<<(N + 63) / 64, 512, 0, stream>>>(M, seg8, padB, hbf, wpkf, bih, bhh, h, out, N);
}